// Round 1
// baseline (102.144 us; speedup 1.0000x reference)
//
#include <hip/hip_runtime.h>
#include <math.h>

// Problem constants
#define H28 28
#define G784 784
#define BATCH 32
#define NOFF 3025   // 55*55 lattice offsets (|di|,|dj| <= 27)
#define NOFFP 3072  // padded to multiple of 64
#define NKEY 1459   // keys di*di+dj*dj in [0, 1458]
#define TPTS 25
#define KMAX 2
#define NFEAT 50    // KMAX*TPTS
#define OUTF 50
#define NCLS 10

#define NBX 16      // blocks per batch for dtm
#define BT 512      // threads per dtm block (8 waves)
#define BT2 512     // threads per pd0 block
#define NWAVE (BT2 / 64)
#define HS 2048     // edge-dedup hash slots (pow2)
#define EMAX 1024   // deduped edge capacity (planar bound ~3*mcnt)

// ---------------------------------------------------------------------------
// Compile-time counting-sorted offset table. d2 reproduces
// f32(sqrt(key)*(224/27))^2 via constexpr Newton sqrt in double.
// ---------------------------------------------------------------------------
struct OffPair { unsigned ij; float d2; };
struct OffTab  { OffPair e[NOFFP]; };

constexpr double csqrt(double x) {
  double r = x * 0.5 + 1.0;
  for (int i = 0; i < 20; i++) r = 0.5 * (r + x / r);
  return r;
}

constexpr OffTab make_offtab() {
  OffTab t{};
  int start[NKEY] = {};
  for (int i = 0; i < NOFF; i++) {
    int di = i / 55 - 27, dj = i % 55 - 27;
    start[di * di + dj * dj]++;
  }
  int run = 0;
  for (int k = 0; k < NKEY; k++) { int h = start[k]; start[k] = run; run += h; }
  for (int i = 0; i < NOFF; i++) {
    int di = i / 55 - 27, dj = i % 55 - 27;
    int key = di * di + dj * dj;
    int pos = start[key]++;
    float sd = (key == 0) ? 0.0f : (float)(csqrt((double)key) * (224.0 / 27.0));
    t.e[pos].ij = ((unsigned)(di & 0xffff)) | (((unsigned)(dj & 0xffff)) << 16);
    t.e[pos].d2 = sd * sd;
  }
  for (int i = NOFF; i < NOFFP; i++) { t.e[i].ij = 0x00640064u; t.e[i].d2 = 0.f; }
  return t;
}

__device__ constexpr OffTab OFFTAB = make_offtab();

// ---------------------------------------------------------------------------
// wave64 inclusive scan via DPP (row_shr 1,2,4,8; row_bcast15/31).
// ---------------------------------------------------------------------------
__device__ __forceinline__ float wave_iscan_f32(float x) {
  int t;
  t = __builtin_amdgcn_update_dpp(0, __float_as_int(x), 0x111, 0xf, 0xf, true);
  x += __int_as_float(t);
  t = __builtin_amdgcn_update_dpp(0, __float_as_int(x), 0x112, 0xf, 0xf, true);
  x += __int_as_float(t);
  t = __builtin_amdgcn_update_dpp(0, __float_as_int(x), 0x114, 0xf, 0xf, true);
  x += __int_as_float(t);
  t = __builtin_amdgcn_update_dpp(0, __float_as_int(x), 0x118, 0xf, 0xf, true);
  x += __int_as_float(t);
  t = __builtin_amdgcn_update_dpp(0, __float_as_int(x), 0x142, 0xa, 0xf, true);
  x += __int_as_float(t);
  t = __builtin_amdgcn_update_dpp(0, __float_as_int(x), 0x143, 0xc, 0xf, true);
  x += __int_as_float(t);
  return x;
}

// ---------------------------------------------------------------------------
// Kernel 1: DTM (unchanged). grid=(BATCH,NBX), block=BT.
// ---------------------------------------------------------------------------
__global__ __launch_bounds__(BT) void dtm_kernel(const float* __restrict__ x,
                                                 float* __restrict__ v,
                                                 int* __restrict__ done_ctr) {
  __shared__ float w_s[G784];
  __shared__ float red[BT];

  const int tid = threadIdx.x;
  const int b   = blockIdx.x;
  const int bx  = blockIdx.y;

  if (b == 0 && bx == 0 && tid == 0) *done_ctr = 0;

  float ps = 0.f;
  for (int i = tid; i < G784; i += BT) {
    float wv = x[b * G784 + i];
    w_s[i] = wv;
    ps += wv;
  }
  red[tid] = ps;
  __syncthreads();
  for (int off = BT / 2; off > 0; off >>= 1) {
    if (tid < off) red[tid] += red[tid + off];
    __syncthreads();
  }
  const float bound = 0.2f * red[0];

  const int wave = tid >> 6;
  const int lane = tid & 63;
  const int slot = bx * 8 + wave;

  for (int g = slot; g < G784; g += NBX * 8) {
    const int i1 = g / H28, j1 = g % H28;
    float cw = 0.f, cwd = 0.f;
    float cwp = 0.f, cwdp = 0.f, dk2 = 0.f;
    bool crossed = false;
    int o = lane;
    unsigned ij = OFFTAB.e[o].ij;
    float d2v   = OFFTAB.e[o].d2;
    for (int base = 0; base < NOFFP && !crossed; base += 64) {
      int onext = o + 64;
      if (onext >= NOFFP) onext = o;
      const unsigned ij_n = OFFTAB.e[onext].ij;
      const float    d2_n = OFFTAB.e[onext].d2;
      const int di = (short)(ij & 0xffffu);
      const int dj = (short)(ij >> 16);
      const int i2 = i1 + di, j2 = j1 + dj;
      const bool inb = ((unsigned)i2 < (unsigned)H28) & ((unsigned)j2 < (unsigned)H28);
      const float wv = inb ? w_s[i2 * H28 + j2] : 0.f;
      const float wd = wv * d2v;
      const float psw = wave_iscan_f32(wv);
      const float psd = wave_iscan_f32(wd);
      const unsigned long long mask = __ballot(cw + psw >= bound);
      if (mask) {
        const int f = __ffsll((unsigned long long)mask) - 1;
        const float psw_f = __shfl(psw, f);
        const float w_f   = __shfl(wv, f);
        const float psd_f = __shfl(psd, f);
        const float wd_f  = __shfl(wd, f);
        dk2  = __shfl(d2v, f);
        cwp  = cw + (psw_f - w_f);
        cwdp = cwd + (psd_f - wd_f);
        crossed = true;
      } else {
        cw  += __int_as_float(__builtin_amdgcn_readlane(__float_as_int(psw), 63));
        cwd += __int_as_float(__builtin_amdgcn_readlane(__float_as_int(psd), 63));
      }
      ij = ij_n; d2v = d2_n; o = onext;
    }
    const float val = (cwdp + (bound - cwp) * dk2) / bound;
    if (lane == 0) v[b * G784 + g] = sqrtf(fmaxf(val, 0.f));
  }
}

// ---------------------------------------------------------------------------
// Kernel 2: pd0 + landscape + (last block) dense head. grid=BATCH, block=BT2.
// Dedup cross-basin edges via LDS hash -> BLOCK-WIDE bitonic sort
// -> claim-based parallel Kruskal (wave 0, rank + halving + oldest-key elder
// rule) -> wave-parallel landscape.
// ---------------------------------------------------------------------------
__device__ __forceinline__ unsigned long long pix_key(const float* val_s, int p) {
  return (((unsigned long long)__float_as_uint(val_s[p])) << 10) | (unsigned)p;
}

__global__ __launch_bounds__(BT2) void pd0_kernel(const float* __restrict__ v,
                                                  float* __restrict__ feats,
                                                  int* __restrict__ done_ctr,
                                                  const float* __restrict__ w_land,
                                                  const float* __restrict__ b_land,
                                                  const float* __restrict__ w_fc,
                                                  const float* __restrict__ b_fc,
                                                  float* __restrict__ out) {
  __shared__ float val_s[G784];
  __shared__ int   ptr_s[G784];
  __shared__ int   parent[G784];
  __shared__ unsigned rank_s[G784];
  __shared__ unsigned claims[G784];
  __shared__ float deathv[G784];
  __shared__ int   mlist[G784];
  __shared__ unsigned long long oldkey[G784];
  __shared__ unsigned htag[HS];
  __shared__ unsigned long long hval[HS];
  __shared__ unsigned long long edges[EMAX];
  __shared__ float redf[BT2];
  __shared__ float wt1[NWAVE][TPTS];
  __shared__ float wt2[NWAVE][TPTS];
  __shared__ int   mcnt_sh, ecnt_sh, last_sh;
  __shared__ float vmax_sh;
  __shared__ float f_s[BATCH * NFEAT];
  __shared__ float xt_s[BATCH * OUTF];

  const int tid = threadIdx.x;
  const int b   = blockIdx.x;
  if (tid == 0) { mcnt_sh = 0; ecnt_sh = 0; }

  // init hash + union-find aux
  for (int i = tid; i < HS; i += BT2) { htag[i] = 0u; hval[i] = ~0ULL; }

  float pm = -1e30f;
  for (int i = tid; i < G784; i += BT2) {
    float xv = v[b * G784 + i];
    val_s[i] = xv;
    pm = fmaxf(pm, xv);
    rank_s[i] = 0u;
    claims[i] = 0xFFFFFFFFu;
  }
  redf[tid] = pm;
  __syncthreads();
  for (int off = BT2 / 2; off > 0; off >>= 1) {
    if (tid < off) redf[tid] = fmaxf(redf[tid], redf[tid + off]);
    __syncthreads();
  }
  if (tid == 0) vmax_sh = redf[0];
  __syncthreads();
  const float vmax = vmax_sh;

  // descending pointer forest; register minima
  for (int p = tid; p < G784; p += BT2) {
    unsigned long long kp = pix_key(val_s, p);
    int i = p / H28, j = p % H28;
    int nbs[4];
    nbs[0] = (i > 0)       ? p - H28 : -1;
    nbs[1] = (i < H28 - 1) ? p + H28 : -1;
    nbs[2] = (j > 0)       ? p - 1   : -1;
    nbs[3] = (j < H28 - 1) ? p + 1   : -1;
    int best = p;
    unsigned long long bk = kp;
    for (int t = 0; t < 4; t++) {
      int q = nbs[t];
      if (q >= 0) {
        unsigned long long kq = pix_key(val_s, q);
        if (kq < bk) { bk = kq; best = q; }
      }
    }
    ptr_s[p]  = best;
    parent[p] = p;
    deathv[p] = vmax;
    if (best == p) {
      oldkey[p] = kp;
      int mi = atomicAdd(&mcnt_sh, 1);
      mlist[mi] = p;
    }
  }
  __syncthreads();

  // pointer doubling -> basin roots
  for (int r = 0; r < 10; r++) {
    for (int p = tid; p < G784; p += BT2) ptr_s[p] = ptr_s[ptr_s[p]];
    __syncthreads();
  }

  // cross-basin edges -> hash dedup: per unordered basin pair keep min
  // (val,p,t) key. Kruskal on per-pair-min simple graph == on multigraph.
  for (int p = tid; p < G784; p += BT2) {
    unsigned long long kp = pix_key(val_s, p);
    int i = p / H28, j = p % H28;
    int nbs[4];
    nbs[0] = (i > 0)       ? p - H28 : -1;
    nbs[1] = (i < H28 - 1) ? p + H28 : -1;
    nbs[2] = (j > 0)       ? p - 1   : -1;
    nbs[3] = (j < H28 - 1) ? p + 1   : -1;
    int bp = ptr_s[p];
    for (int t = 0; t < 4; t++) {
      int q = nbs[t];
      if (q >= 0) {
        unsigned long long kq = pix_key(val_s, q);
        int bq = ptr_s[q];
        if (kq < kp && bq != bp) {
          unsigned long long key =
              (((unsigned long long)__float_as_uint(val_s[p])) << 32) |
              (((unsigned long long)(unsigned)p) << 22) |
              (((unsigned long long)(unsigned)t) << 20) |
              (((unsigned long long)(unsigned)bp) << 10) |
              ((unsigned long long)(unsigned)bq);
          unsigned lo = (bp < bq) ? (unsigned)bp : (unsigned)bq;
          unsigned hi = (bp < bq) ? (unsigned)bq : (unsigned)bp;
          unsigned pairid = (lo << 10) | hi;
          unsigned idx = (pairid * 2654435761u) >> 21;   // HS=2048
          for (;;) {
            unsigned t0 = atomicCAS(&htag[idx], 0u, pairid + 1u);
            if (t0 == 0u || t0 == pairid + 1u) { atomicMin(&hval[idx], key); break; }
            idx = (idx + 1) & (HS - 1);
          }
        }
      }
    }
  }
  __syncthreads();

  // compact hash -> edges
  for (int i = tid; i < HS; i += BT2) {
    if (htag[i]) {
      int e = atomicAdd(&ecnt_sh, 1);
      if (e < EMAX) edges[e] = hval[i];
    }
  }
  __syncthreads();
  const int ne   = (ecnt_sh < EMAX) ? ecnt_sh : EMAX;
  const int mcnt = mcnt_sh;
  const int wave = tid >> 6;
  const int lane = tid & 63;

  // ---- BLOCK-WIDE bitonic sort (ne, n2 are block-uniform; pairs within a
  // (kk,jj) step are disjoint so each pair is owned by exactly one thread) ----
  if (ne > 1) {
    int n2 = 1;
    while (n2 < ne) n2 <<= 1;
    for (int i = ne + tid; i < n2; i += BT2) edges[i] = ~0ULL;
    __syncthreads();
    for (int kk = 2; kk <= n2; kk <<= 1) {
      for (int jj = kk >> 1; jj > 0; jj >>= 1) {
        for (int i = tid; i < n2; i += BT2) {
          int ixj = i ^ jj;
          if (ixj > i) {
            unsigned long long a = edges[i], c = edges[ixj];
            bool up = ((i & kk) == 0);
            if ((a > c) == up) { edges[i] = c; edges[ixj] = a; }
          }
        }
        __syncthreads();
      }
    }
  }

  // ---- wave 0: claim-based parallel Kruskal, exact sequential-order
  // semantics (wave-synchronous; fences not barriers) ----
  if (wave == 0) {
    int merged = 0;
    const int target = mcnt - 1;
    for (int base = 0; base < ne && merged < target; base += 64) {
      const int idx = base + lane;
      bool unresolved = (idx < ne);
      const unsigned long long e = unresolved ? edges[idx] : 0ULL;
      const int A  = (int)((e >> 10) & 1023u);
      const int Bq = (int)(e & 1023u);
      const float ev = __uint_as_float((unsigned)(e >> 32));
      for (;;) {
        int rA = A, rB = Bq;
        if (unresolved) {
          int xx = A;
          for (;;) { int p1 = parent[xx]; if (p1 == xx) break;
                     int p2 = parent[p1]; parent[xx] = p2; xx = p2; }
          rA = xx;
          xx = Bq;
          for (;;) { int p1 = parent[xx]; if (p1 == xx) break;
                     int p2 = parent[p1]; parent[xx] = p2; xx = p2; }
          rB = xx;
        }
        bool crossing = unresolved && (rA != rB);
        if (unresolved && !crossing) unresolved = false;
        if (__ballot(crossing) == 0ULL) break;
        if (crossing) {
          atomicMin(&claims[rA], (unsigned)lane);
          atomicMin(&claims[rB], (unsigned)lane);
        }
        __threadfence_block();
        bool win = crossing && claims[rA] == (unsigned)lane
                            && claims[rB] == (unsigned)lane;
        __threadfence_block();
        if (crossing) { claims[rA] = 0xFFFFFFFFu; claims[rB] = 0xFFFFFFFFu; }
        if (win) {
          unsigned long long ka = oldkey[rA], kb = oldkey[rB];
          unsigned ra_ = rank_s[rA], rb_ = rank_s[rB];
          int big   = (ra_ > rb_) ? rA : ((rb_ > ra_) ? rB : ((rA < rB) ? rA : rB));
          int small = (big == rA) ? rB : rA;
          parent[small] = big;
          if (ra_ == rb_) rank_s[big] = ra_ + 1u;
          unsigned long long okmin = (ka < kb) ? ka : kb;
          unsigned long long okmax = (ka < kb) ? kb : ka;
          oldkey[big] = okmin;
          int dying = (int)(okmax & 1023u);
          deathv[dying] = ev;
          unresolved = false;
        }
        __threadfence_block();
        merged += (int)__popcll(__ballot(win));
        if (merged >= target) break;
      }
    }
  }
  __syncthreads();

  // ---- wave-parallel landscape: each wave scans a strided 1/NWAVE of the
  // minima (lanes 0..24 own one t each), then wave 0 merges partial top-2s ----
  if (lane < TPTS) {
    float ti = (float)((double)lane * (100.0 / 24.0));
    float t1 = 0.f, t2 = 0.f;
    for (int ii = wave; ii < mcnt; ii += NWAVE) {
      int m = mlist[ii];
      float tent = fminf(ti - val_s[m], deathv[m] - ti);
      tent = fmaxf(tent, 0.f);
      if (tent > t1)      { t2 = t1; t1 = tent; }
      else if (tent > t2) { t2 = tent; }
    }
    wt1[wave][lane] = t1;
    wt2[wave][lane] = t2;
  }
  __syncthreads();
  if (wave == 0 && lane < TPTS) {
    float t1 = 0.f, t2 = 0.f;
    for (int w = 0; w < NWAVE; w++) {
      float a = wt1[w][lane], c = wt2[w][lane];   // a >= c
      if (a >= t1) { t2 = fmaxf(t1, c); t1 = a; }
      else         { t2 = fmaxf(t2, a); }
    }
    feats[b * NFEAT + lane]        = t1;
    feats[b * NFEAT + TPTS + lane] = t2;
  }

  // ---- last block computes the dense head ----
  __threadfence();
  __syncthreads();
  if (tid == 0) last_sh = (atomicAdd(done_ctr, 1) == BATCH - 1) ? 1 : 0;
  __syncthreads();
  if (!last_sh) return;
  __threadfence();

  for (int i = tid; i < BATCH * NFEAT; i += BT2) f_s[i] = feats[i];
  __syncthreads();
  for (int idx = tid; idx < BATCH * OUTF; idx += BT2) {
    int bb = idx / OUTF, ff = idx % OUTF;
    float acc = b_land[ff];
    const float* wr = w_land + ff * NFEAT;
    const float* fr = f_s + bb * NFEAT;
    for (int j = 0; j < NFEAT; j++) acc += fr[j] * wr[j];
    xt_s[idx] = acc;
  }
  __syncthreads();
  if (tid < OUTF) {
    float s = 0.f;
    for (int bb = 0; bb < BATCH; bb++) s += fabsf(xt_s[bb * OUTF + tid]);
    out[BATCH * NCLS + tid] = s;
  }
  for (int idx = tid; idx < BATCH * NCLS; idx += BT2) {
    int bb = idx / NCLS, cc = idx % NCLS;
    float acc = b_fc[cc];
    const float* wr = w_fc + cc * OUTF;
    const float* xr = xt_s + bb * OUTF;
    for (int ff = 0; ff < OUTF; ff++) acc += fmaxf(xr[ff], 0.f) * wr[ff];
    out[bb * NCLS + cc] = acc;
  }
}

// ---------------------------------------------------------------------------
extern "C" void kernel_launch(void* const* d_in, const int* in_sizes, int n_in,
                              void* d_out, int out_size, void* d_ws, size_t ws_size,
                              hipStream_t stream) {
  (void)in_sizes; (void)n_in; (void)out_size; (void)ws_size;
  const float* x      = (const float*)d_in[0];   // [32,1,28,28]
  const float* w_land = (const float*)d_in[1];   // [50,50]
  const float* b_land = (const float*)d_in[2];   // [50]
  const float* w_fc   = (const float*)d_in[3];   // [10,50]
  const float* b_fc   = (const float*)d_in[4];   // [10]
  float* out   = (float*)d_out;                  // [32*10] out then [50] signal
  float* v     = (float*)d_ws;                   // [32*784]
  float* feats = v + BATCH * G784;               // [32*50]
  int*   done  = (int*)(feats + BATCH * NFEAT);  // [1]

  dim3 g1(BATCH, NBX);
  dtm_kernel<<<g1, BT, 0, stream>>>(x, v, done);
  pd0_kernel<<<BATCH, BT2, 0, stream>>>(v, feats, done,
                                        w_land, b_land, w_fc, b_fc, out);
}

// Round 2
// 101.019 us; speedup vs baseline: 1.0111x; 1.0111x over previous
//
#include <hip/hip_runtime.h>
#include <math.h>

// Problem constants
#define H28 28
#define G784 784
#define BATCH 32
#define NOFF 3025   // 55*55 lattice offsets (|di|,|dj| <= 27)
#define NOFFP 3072  // padded to multiple of 64
#define NKEY 1459   // keys di*di+dj*dj in [0, 1458]
#define TPTS 25
#define KMAX 2
#define NFEAT 50    // KMAX*TPTS
#define OUTF 50
#define NCLS 10

#define NBX 16      // blocks per batch for dtm
#define BT 512      // threads per dtm block (8 waves)
#define BT2 512     // threads per pd0 block
#define NWAVE (BT2 / 64)
#define HS 2048     // edge-dedup hash slots (pow2)
#define EMAX 1024   // deduped edge capacity (planar bound ~3*mcnt)

// ---------------------------------------------------------------------------
// Compile-time counting-sorted offset table. d2 reproduces
// f32(sqrt(key)*(224/27))^2 via constexpr Newton sqrt in double.
// ---------------------------------------------------------------------------
struct OffPair { unsigned ij; float d2; };
struct OffTab  { OffPair e[NOFFP]; };

constexpr double csqrt(double x) {
  double r = x * 0.5 + 1.0;
  for (int i = 0; i < 20; i++) r = 0.5 * (r + x / r);
  return r;
}

constexpr OffTab make_offtab() {
  OffTab t{};
  int start[NKEY] = {};
  for (int i = 0; i < NOFF; i++) {
    int di = i / 55 - 27, dj = i % 55 - 27;
    start[di * di + dj * dj]++;
  }
  int run = 0;
  for (int k = 0; k < NKEY; k++) { int h = start[k]; start[k] = run; run += h; }
  for (int i = 0; i < NOFF; i++) {
    int di = i / 55 - 27, dj = i % 55 - 27;
    int key = di * di + dj * dj;
    int pos = start[key]++;
    float sd = (key == 0) ? 0.0f : (float)(csqrt((double)key) * (224.0 / 27.0));
    t.e[pos].ij = ((unsigned)(di & 0xffff)) | (((unsigned)(dj & 0xffff)) << 16);
    t.e[pos].d2 = sd * sd;
  }
  for (int i = NOFF; i < NOFFP; i++) { t.e[i].ij = 0x00640064u; t.e[i].d2 = 0.f; }
  return t;
}

__device__ constexpr OffTab OFFTAB = make_offtab();

// ---------------------------------------------------------------------------
// wave64 inclusive scan via DPP (row_shr 1,2,4,8; row_bcast15/31).
// ---------------------------------------------------------------------------
__device__ __forceinline__ float wave_iscan_f32(float x) {
  int t;
  t = __builtin_amdgcn_update_dpp(0, __float_as_int(x), 0x111, 0xf, 0xf, true);
  x += __int_as_float(t);
  t = __builtin_amdgcn_update_dpp(0, __float_as_int(x), 0x112, 0xf, 0xf, true);
  x += __int_as_float(t);
  t = __builtin_amdgcn_update_dpp(0, __float_as_int(x), 0x114, 0xf, 0xf, true);
  x += __int_as_float(t);
  t = __builtin_amdgcn_update_dpp(0, __float_as_int(x), 0x118, 0xf, 0xf, true);
  x += __int_as_float(t);
  t = __builtin_amdgcn_update_dpp(0, __float_as_int(x), 0x142, 0xa, 0xf, true);
  x += __int_as_float(t);
  t = __builtin_amdgcn_update_dpp(0, __float_as_int(x), 0x143, 0xc, 0xf, true);
  x += __int_as_float(t);
  return x;
}

// ---------------------------------------------------------------------------
// Kernel 1: DTM. grid=(BATCH,NBX), block=BT.
// Sum-reduce: LDS tree to 64 partials, then wave-0 shuffle tree with the SAME
// pairing/order as the LDS tree (bit-identical bound), 4 barriers vs 9.
// ---------------------------------------------------------------------------
__global__ __launch_bounds__(BT) void dtm_kernel(const float* __restrict__ x,
                                                 float* __restrict__ v,
                                                 int* __restrict__ done_ctr) {
  __shared__ float w_s[G784];
  __shared__ float red[BT];

  const int tid = threadIdx.x;
  const int b   = blockIdx.x;
  const int bx  = blockIdx.y;

  if (b == 0 && bx == 0 && tid == 0) *done_ctr = 0;

  float ps = 0.f;
  for (int i = tid; i < G784; i += BT) {
    float wv = x[b * G784 + i];
    w_s[i] = wv;
    ps += wv;
  }
  red[tid] = ps;
  __syncthreads();
  if (tid < 256) red[tid] += red[tid + 256];
  __syncthreads();
  if (tid < 128) red[tid] += red[tid + 128];
  __syncthreads();
  if (tid < 64)  red[tid] += red[tid + 64];
  __syncthreads();
  if (tid < 64) {
    float vv = red[tid];
    vv += __shfl_down(vv, 32);
    vv += __shfl_down(vv, 16);
    vv += __shfl_down(vv, 8);
    vv += __shfl_down(vv, 4);
    vv += __shfl_down(vv, 2);
    vv += __shfl_down(vv, 1);
    if (tid == 0) red[0] = vv;
  }
  __syncthreads();
  const float bound = 0.2f * red[0];

  const int wave = tid >> 6;
  const int lane = tid & 63;
  const int slot = bx * 8 + wave;

  for (int g = slot; g < G784; g += NBX * 8) {
    const int i1 = g / H28, j1 = g % H28;
    float cw = 0.f, cwd = 0.f;
    float cwp = 0.f, cwdp = 0.f, dk2 = 0.f;
    bool crossed = false;
    int o = lane;
    unsigned ij = OFFTAB.e[o].ij;
    float d2v   = OFFTAB.e[o].d2;
    for (int base = 0; base < NOFFP && !crossed; base += 64) {
      int onext = o + 64;
      if (onext >= NOFFP) onext = o;
      const unsigned ij_n = OFFTAB.e[onext].ij;
      const float    d2_n = OFFTAB.e[onext].d2;
      const int di = (short)(ij & 0xffffu);
      const int dj = (short)(ij >> 16);
      const int i2 = i1 + di, j2 = j1 + dj;
      const bool inb = ((unsigned)i2 < (unsigned)H28) & ((unsigned)j2 < (unsigned)H28);
      const float wv = inb ? w_s[i2 * H28 + j2] : 0.f;
      const float wd = wv * d2v;
      const float psw = wave_iscan_f32(wv);
      const float psd = wave_iscan_f32(wd);
      const unsigned long long mask = __ballot(cw + psw >= bound);
      if (mask) {
        const int f = __ffsll((unsigned long long)mask) - 1;
        const float psw_f = __shfl(psw, f);
        const float w_f   = __shfl(wv, f);
        const float psd_f = __shfl(psd, f);
        const float wd_f  = __shfl(wd, f);
        dk2  = __shfl(d2v, f);
        cwp  = cw + (psw_f - w_f);
        cwdp = cwd + (psd_f - wd_f);
        crossed = true;
      } else {
        cw  += __int_as_float(__builtin_amdgcn_readlane(__float_as_int(psw), 63));
        cwd += __int_as_float(__builtin_amdgcn_readlane(__float_as_int(psd), 63));
      }
      ij = ij_n; d2v = d2_n; o = onext;
    }
    const float val = (cwdp + (bound - cwp) * dk2) / bound;
    if (lane == 0) v[b * G784 + g] = sqrtf(fmaxf(val, 0.f));
  }
}

// ---------------------------------------------------------------------------
// Kernel 2: pd0 + landscape + (last block) dense head. grid=BATCH, block=BT2.
// Dedup cross-basin edges via LDS hash -> register-resident hybrid bitonic
// (jj<=32 stages via shfl_xor, no barrier; jj>=64 via LDS, 12 barriers total)
// -> claim-based parallel Kruskal (wave 0) -> wave-parallel landscape.
// ---------------------------------------------------------------------------
__device__ __forceinline__ unsigned long long pix_key(const float* val_s, int p) {
  return (((unsigned long long)__float_as_uint(val_s[p])) << 10) | (unsigned)p;
}

__global__ __launch_bounds__(BT2) void pd0_kernel(const float* __restrict__ v,
                                                  float* __restrict__ feats,
                                                  int* __restrict__ done_ctr,
                                                  const float* __restrict__ w_land,
                                                  const float* __restrict__ b_land,
                                                  const float* __restrict__ w_fc,
                                                  const float* __restrict__ b_fc,
                                                  float* __restrict__ out) {
  __shared__ float val_s[G784];
  __shared__ int   ptr_s[G784];
  __shared__ int   parent[G784];
  __shared__ unsigned rank_s[G784];
  __shared__ unsigned claims[G784];
  __shared__ float deathv[G784];
  __shared__ int   mlist[G784];
  __shared__ unsigned long long oldkey[G784];
  __shared__ unsigned htag[HS];
  __shared__ unsigned long long hval[HS];
  __shared__ unsigned long long edges[EMAX];
  __shared__ float redf[NWAVE];
  __shared__ float wt1[NWAVE][TPTS];
  __shared__ float wt2[NWAVE][TPTS];
  __shared__ int   mcnt_sh, ecnt_sh, last_sh;
  __shared__ float vmax_sh;
  __shared__ float f_s[BATCH * NFEAT];
  __shared__ float xt_s[BATCH * OUTF];

  const int tid = threadIdx.x;
  const int b   = blockIdx.x;
  const int wave = tid >> 6;
  const int lane = tid & 63;
  if (tid == 0) { mcnt_sh = 0; ecnt_sh = 0; }

  // init hash + union-find aux
  for (int i = tid; i < HS; i += BT2) { htag[i] = 0u; hval[i] = ~0ULL; }

  float pm = -1e30f;
  for (int i = tid; i < G784; i += BT2) {
    float xv = v[b * G784 + i];
    val_s[i] = xv;
    pm = fmaxf(pm, xv);
    rank_s[i] = 0u;
    claims[i] = 0xFFFFFFFFu;
  }
  // wave-level max (fmax is order-insensitive), then 8-way combine: 2 barriers
  pm = fmaxf(pm, __shfl_down(pm, 32));
  pm = fmaxf(pm, __shfl_down(pm, 16));
  pm = fmaxf(pm, __shfl_down(pm, 8));
  pm = fmaxf(pm, __shfl_down(pm, 4));
  pm = fmaxf(pm, __shfl_down(pm, 2));
  pm = fmaxf(pm, __shfl_down(pm, 1));
  if (lane == 0) redf[wave] = pm;
  __syncthreads();
  if (tid == 0) {
    float m = redf[0];
    for (int w = 1; w < NWAVE; w++) m = fmaxf(m, redf[w]);
    vmax_sh = m;
  }
  __syncthreads();
  const float vmax = vmax_sh;

  // descending pointer forest; register minima
  for (int p = tid; p < G784; p += BT2) {
    unsigned long long kp = pix_key(val_s, p);
    int i = p / H28, j = p % H28;
    int nbs[4];
    nbs[0] = (i > 0)       ? p - H28 : -1;
    nbs[1] = (i < H28 - 1) ? p + H28 : -1;
    nbs[2] = (j > 0)       ? p - 1   : -1;
    nbs[3] = (j < H28 - 1) ? p + 1   : -1;
    int best = p;
    unsigned long long bk = kp;
    for (int t = 0; t < 4; t++) {
      int q = nbs[t];
      if (q >= 0) {
        unsigned long long kq = pix_key(val_s, q);
        if (kq < bk) { bk = kq; best = q; }
      }
    }
    ptr_s[p]  = best;
    parent[p] = p;
    deathv[p] = vmax;
    if (best == p) {
      oldkey[p] = kp;
      int mi = atomicAdd(&mcnt_sh, 1);
      mlist[mi] = p;
    }
  }
  __syncthreads();

  // pointer quadrupling -> basin roots. 4^5=1024>784; in-place races are
  // monotone-safe (any mix of old/new pointers still points to an ancestor).
  for (int r = 0; r < 5; r++) {
    for (int p = tid; p < G784; p += BT2) {
      int a = ptr_s[p];
      a = ptr_s[a];
      a = ptr_s[a];
      a = ptr_s[a];
      ptr_s[p] = a;
    }
    __syncthreads();
  }

  // cross-basin edges -> hash dedup: per unordered basin pair keep min
  // (val,p,t) key. Kruskal on per-pair-min simple graph == on multigraph.
  for (int p = tid; p < G784; p += BT2) {
    unsigned long long kp = pix_key(val_s, p);
    int i = p / H28, j = p % H28;
    int nbs[4];
    nbs[0] = (i > 0)       ? p - H28 : -1;
    nbs[1] = (i < H28 - 1) ? p + H28 : -1;
    nbs[2] = (j > 0)       ? p - 1   : -1;
    nbs[3] = (j < H28 - 1) ? p + 1   : -1;
    int bp = ptr_s[p];
    for (int t = 0; t < 4; t++) {
      int q = nbs[t];
      if (q >= 0) {
        unsigned long long kq = pix_key(val_s, q);
        int bq = ptr_s[q];
        if (kq < kp && bq != bp) {
          unsigned long long key =
              (((unsigned long long)__float_as_uint(val_s[p])) << 32) |
              (((unsigned long long)(unsigned)p) << 22) |
              (((unsigned long long)(unsigned)t) << 20) |
              (((unsigned long long)(unsigned)bp) << 10) |
              ((unsigned long long)(unsigned)bq);
          unsigned lo = (bp < bq) ? (unsigned)bp : (unsigned)bq;
          unsigned hi = (bp < bq) ? (unsigned)bq : (unsigned)bp;
          unsigned pairid = (lo << 10) | hi;
          unsigned idx = (pairid * 2654435761u) >> 21;   // HS=2048
          for (;;) {
            unsigned t0 = atomicCAS(&htag[idx], 0u, pairid + 1u);
            if (t0 == 0u || t0 == pairid + 1u) { atomicMin(&hval[idx], key); break; }
            idx = (idx + 1) & (HS - 1);
          }
        }
      }
    }
  }
  __syncthreads();

  // compact hash -> edges
  for (int i = tid; i < HS; i += BT2) {
    if (htag[i]) {
      int e = atomicAdd(&ecnt_sh, 1);
      if (e < EMAX) edges[e] = hval[i];
    }
  }
  __syncthreads();
  const int ne   = (ecnt_sh < EMAX) ? ecnt_sh : EMAX;
  const int mcnt = mcnt_sh;

  // ---- register-resident hybrid bitonic sort (ascending) ----
  // Common case ne <= 512: one element per thread; stages with jj<=32 are
  // intra-wave shfl_xor (no LDS, no barrier); jj>=64 via LDS (2 barriers each:
  // 6 exchanges -> 12 barriers). Same comparator network as classic bitonic.
  if (ne > 1 && ne <= BT2) {
    unsigned long long e = (tid < ne) ? edges[tid] : ~0ULL;
    __syncthreads();                     // protect edges[] before re-use as exchange buffer
    for (int kk = 2; kk <= BT2; kk <<= 1) {
      const bool up = ((tid & kk) == 0);
      for (int jj = kk >> 1; jj >= 64; jj >>= 1) {
        edges[tid] = e;
        __syncthreads();
        unsigned long long p = edges[tid ^ jj];
        __syncthreads();
        const bool lower = ((tid & jj) == 0);
        const bool keepmin = (up == lower);
        e = keepmin ? ((e < p) ? e : p) : ((e > p) ? e : p);
      }
      int jj0 = (kk >> 1 < 32) ? (kk >> 1) : 32;
      for (int jj = jj0; jj >= 1; jj >>= 1) {
        unsigned long long p = __shfl_xor((long long)e, jj, 64);
        const bool lower = ((tid & jj) == 0);
        const bool keepmin = (up == lower);
        e = keepmin ? ((e < p) ? e : p) : ((e > p) ? e : p);
      }
    }
    edges[tid] = e;
    __syncthreads();
  } else if (ne > 1) {
    // fallback: generic block-wide LDS bitonic (rare: ne > 512)
    int n2 = 1;
    while (n2 < ne) n2 <<= 1;
    for (int i = ne + tid; i < n2; i += BT2) edges[i] = ~0ULL;
    __syncthreads();
    for (int kk = 2; kk <= n2; kk <<= 1) {
      for (int jj = kk >> 1; jj > 0; jj >>= 1) {
        for (int i = tid; i < n2; i += BT2) {
          int ixj = i ^ jj;
          if (ixj > i) {
            unsigned long long a = edges[i], c = edges[ixj];
            bool up = ((i & kk) == 0);
            if ((a > c) == up) { edges[i] = c; edges[ixj] = a; }
          }
        }
        __syncthreads();
      }
    }
  }

  // ---- wave 0: claim-based parallel Kruskal, exact sequential-order
  // semantics (wave-synchronous; fences not barriers) ----
  if (wave == 0) {
    int merged = 0;
    const int target = mcnt - 1;
    for (int base = 0; base < ne && merged < target; base += 64) {
      const int idx = base + lane;
      bool unresolved = (idx < ne);
      const unsigned long long e = unresolved ? edges[idx] : 0ULL;
      const int A  = (int)((e >> 10) & 1023u);
      const int Bq = (int)(e & 1023u);
      const float ev = __uint_as_float((unsigned)(e >> 32));
      for (;;) {
        int rA = A, rB = Bq;
        if (unresolved) {
          int xx = A;
          for (;;) { int p1 = parent[xx]; if (p1 == xx) break;
                     int p2 = parent[p1]; parent[xx] = p2; xx = p2; }
          rA = xx;
          xx = Bq;
          for (;;) { int p1 = parent[xx]; if (p1 == xx) break;
                     int p2 = parent[p1]; parent[xx] = p2; xx = p2; }
          rB = xx;
        }
        bool crossing = unresolved && (rA != rB);
        if (unresolved && !crossing) unresolved = false;
        if (__ballot(crossing) == 0ULL) break;
        if (crossing) {
          atomicMin(&claims[rA], (unsigned)lane);
          atomicMin(&claims[rB], (unsigned)lane);
        }
        __threadfence_block();
        bool win = crossing && claims[rA] == (unsigned)lane
                            && claims[rB] == (unsigned)lane;
        __threadfence_block();
        if (crossing) { claims[rA] = 0xFFFFFFFFu; claims[rB] = 0xFFFFFFFFu; }
        if (win) {
          unsigned long long ka = oldkey[rA], kb = oldkey[rB];
          unsigned ra_ = rank_s[rA], rb_ = rank_s[rB];
          int big   = (ra_ > rb_) ? rA : ((rb_ > ra_) ? rB : ((rA < rB) ? rA : rB));
          int small = (big == rA) ? rB : rA;
          parent[small] = big;
          if (ra_ == rb_) rank_s[big] = ra_ + 1u;
          unsigned long long okmin = (ka < kb) ? ka : kb;
          unsigned long long okmax = (ka < kb) ? kb : ka;
          oldkey[big] = okmin;
          int dying = (int)(okmax & 1023u);
          deathv[dying] = ev;
          unresolved = false;
        }
        __threadfence_block();
        merged += (int)__popcll(__ballot(win));
        if (merged >= target) break;
      }
    }
  }
  __syncthreads();

  // ---- wave-parallel landscape: each wave scans a strided 1/NWAVE of the
  // minima (lanes 0..24 own one t each), then wave 0 merges partial top-2s ----
  if (lane < TPTS) {
    float ti = (float)((double)lane * (100.0 / 24.0));
    float t1 = 0.f, t2 = 0.f;
    for (int ii = wave; ii < mcnt; ii += NWAVE) {
      int m = mlist[ii];
      float tent = fminf(ti - val_s[m], deathv[m] - ti);
      tent = fmaxf(tent, 0.f);
      if (tent > t1)      { t2 = t1; t1 = tent; }
      else if (tent > t2) { t2 = tent; }
    }
    wt1[wave][lane] = t1;
    wt2[wave][lane] = t2;
  }
  __syncthreads();
  if (wave == 0 && lane < TPTS) {
    float t1 = 0.f, t2 = 0.f;
    for (int w = 0; w < NWAVE; w++) {
      float a = wt1[w][lane], c = wt2[w][lane];   // a >= c
      if (a >= t1) { t2 = fmaxf(t1, c); t1 = a; }
      else         { t2 = fmaxf(t2, a); }
    }
    feats[b * NFEAT + lane]        = t1;
    feats[b * NFEAT + TPTS + lane] = t2;
  }

  // ---- last block computes the dense head ----
  __threadfence();
  __syncthreads();
  if (tid == 0) last_sh = (atomicAdd(done_ctr, 1) == BATCH - 1) ? 1 : 0;
  __syncthreads();
  if (!last_sh) return;
  __threadfence();

  for (int i = tid; i < BATCH * NFEAT; i += BT2) f_s[i] = feats[i];
  __syncthreads();
  for (int idx = tid; idx < BATCH * OUTF; idx += BT2) {
    int bb = idx / OUTF, ff = idx % OUTF;
    float acc = b_land[ff];
    const float* wr = w_land + ff * NFEAT;
    const float* fr = f_s + bb * NFEAT;
    for (int j = 0; j < NFEAT; j++) acc += fr[j] * wr[j];
    xt_s[idx] = acc;
  }
  __syncthreads();
  if (tid < OUTF) {
    float s = 0.f;
    for (int bb = 0; bb < BATCH; bb++) s += fabsf(xt_s[bb * OUTF + tid]);
    out[BATCH * NCLS + tid] = s;
  }
  for (int idx = tid; idx < BATCH * NCLS; idx += BT2) {
    int bb = idx / NCLS, cc = idx % NCLS;
    float acc = b_fc[cc];
    const float* wr = w_fc + cc * OUTF;
    const float* xr = xt_s + bb * OUTF;
    for (int ff = 0; ff < OUTF; ff++) acc += fmaxf(xr[ff], 0.f) * wr[ff];
    out[bb * NCLS + cc] = acc;
  }
}

// ---------------------------------------------------------------------------
extern "C" void kernel_launch(void* const* d_in, const int* in_sizes, int n_in,
                              void* d_out, int out_size, void* d_ws, size_t ws_size,
                              hipStream_t stream) {
  (void)in_sizes; (void)n_in; (void)out_size; (void)ws_size;
  const float* x      = (const float*)d_in[0];   // [32,1,28,28]
  const float* w_land = (const float*)d_in[1];   // [50,50]
  const float* b_land = (const float*)d_in[2];   // [50]
  const float* w_fc   = (const float*)d_in[3];   // [10,50]
  const float* b_fc   = (const float*)d_in[4];   // [10]
  float* out   = (float*)d_out;                  // [32*10] out then [50] signal
  float* v     = (float*)d_ws;                   // [32*784]
  float* feats = v + BATCH * G784;               // [32*50]
  int*   done  = (int*)(feats + BATCH * NFEAT);  // [1]

  dim3 g1(BATCH, NBX);
  dtm_kernel<<<g1, BT, 0, stream>>>(x, v, done);
  pd0_kernel<<<BATCH, BT2, 0, stream>>>(v, feats, done,
                                        w_land, b_land, w_fc, b_fc, out);
}